// Round 2
// baseline (450.592 us; speedup 1.0000x reference)
//
#include <hip/hip_runtime.h>
#include <hip/hip_bf16.h>
#include <stdint.h>
#include <stddef.h>

typedef __attribute__((ext_vector_type(8))) short s8v;       // 8 x bf16 (as i16)
typedef __attribute__((ext_vector_type(4))) float f32x4;
typedef __attribute__((ext_vector_type(4))) uint32_t u32x4;
typedef __attribute__((ext_vector_type(4))) unsigned short u16x4;

#define KDIM 4096
#define NH   128
#define MMEM 50000
#define BFEAT 64

static __device__ __forceinline__ unsigned short f2bf(float f) {
  union { float f; uint32_t u; } c; c.f = f;
  uint32_t u = c.u;
  return (unsigned short)((u + 0x7FFFu + ((u >> 16) & 1u)) >> 16);  // RNE
}

static __device__ __forceinline__ short f2bfs(float f) {
  __hip_bfloat16 h = __float2bfloat16(f);   // compiler fuses pairs to v_cvt_pk_bf16_f32
  short s;
  __builtin_memcpy(&s, &h, sizeof(s));
  return s;
}

// ---- Kernel 0: hash_W f32 -> bf16 ------------------------------------------
__global__ __launch_bounds__(256) void convert_w_kernel(
    const float* __restrict__ W, unsigned short* __restrict__ Wb) {
  int i = blockIdx.x * 256 + threadIdx.x;          // float4 index, 131072 total
  f32x4 v = reinterpret_cast<const f32x4*>(W)[i];
  u16x4 o;
  o[0] = f2bf(v[0]); o[1] = f2bf(v[1]); o[2] = f2bf(v[2]); o[3] = f2bf(v[3]);
  reinterpret_cast<u16x4*>(Wb)[i] = o;
}

// ---- Kernel A: LDS-free streaming bf16 MFMA, wave = 32 rows x 128 cols ------
// A fragments loaded straight from global f32 (coalesced: 16 rows x 128B/step),
// B fragments from L2-resident Wb. No LDS, no barriers. Ballot-packed epilogue.

struct Stage {
  f32x4 a0lo, a0hi, a1lo, a1hi;   // 32 f32 of A (2 row-frags x 8 f32/lane)
  s8v   b0, b1, b2, b3, b4, b5, b6, b7;  // 8 col-frags of B
};

static __device__ __forceinline__ void ldstage(
    Stage& st, const float* pa0, const float* pa1,
    const unsigned short* pb, int kt) {
  const f32x4* q0 = reinterpret_cast<const f32x4*>(pa0 + kt);
  st.a0lo = q0[0]; st.a0hi = q0[1];
  const f32x4* q1 = reinterpret_cast<const f32x4*>(pa1 + kt);
  st.a1lo = q1[0]; st.a1hi = q1[1];
  st.b0 = *reinterpret_cast<const s8v*>(pb + 0 * 65536 + kt);
  st.b1 = *reinterpret_cast<const s8v*>(pb + 1 * 65536 + kt);
  st.b2 = *reinterpret_cast<const s8v*>(pb + 2 * 65536 + kt);
  st.b3 = *reinterpret_cast<const s8v*>(pb + 3 * 65536 + kt);
  st.b4 = *reinterpret_cast<const s8v*>(pb + 4 * 65536 + kt);
  st.b5 = *reinterpret_cast<const s8v*>(pb + 5 * 65536 + kt);
  st.b6 = *reinterpret_cast<const s8v*>(pb + 6 * 65536 + kt);
  st.b7 = *reinterpret_cast<const s8v*>(pb + 7 * 65536 + kt);
}

static __device__ __forceinline__ void compute(const Stage& st, f32x4 acc[2][8]) {
  s8v a0, a1;
#pragma unroll
  for (int q = 0; q < 4; ++q) {
    a0[q]     = f2bfs(st.a0lo[q]);
    a0[q + 4] = f2bfs(st.a0hi[q]);
    a1[q]     = f2bfs(st.a1lo[q]);
    a1[q + 4] = f2bfs(st.a1hi[q]);
  }
  acc[0][0] = __builtin_amdgcn_mfma_f32_16x16x32_bf16(a0, st.b0, acc[0][0], 0, 0, 0);
  acc[1][0] = __builtin_amdgcn_mfma_f32_16x16x32_bf16(a1, st.b0, acc[1][0], 0, 0, 0);
  acc[0][1] = __builtin_amdgcn_mfma_f32_16x16x32_bf16(a0, st.b1, acc[0][1], 0, 0, 0);
  acc[1][1] = __builtin_amdgcn_mfma_f32_16x16x32_bf16(a1, st.b1, acc[1][1], 0, 0, 0);
  acc[0][2] = __builtin_amdgcn_mfma_f32_16x16x32_bf16(a0, st.b2, acc[0][2], 0, 0, 0);
  acc[1][2] = __builtin_amdgcn_mfma_f32_16x16x32_bf16(a1, st.b2, acc[1][2], 0, 0, 0);
  acc[0][3] = __builtin_amdgcn_mfma_f32_16x16x32_bf16(a0, st.b3, acc[0][3], 0, 0, 0);
  acc[1][3] = __builtin_amdgcn_mfma_f32_16x16x32_bf16(a1, st.b3, acc[1][3], 0, 0, 0);
  acc[0][4] = __builtin_amdgcn_mfma_f32_16x16x32_bf16(a0, st.b4, acc[0][4], 0, 0, 0);
  acc[1][4] = __builtin_amdgcn_mfma_f32_16x16x32_bf16(a1, st.b4, acc[1][4], 0, 0, 0);
  acc[0][5] = __builtin_amdgcn_mfma_f32_16x16x32_bf16(a0, st.b5, acc[0][5], 0, 0, 0);
  acc[1][5] = __builtin_amdgcn_mfma_f32_16x16x32_bf16(a1, st.b5, acc[1][5], 0, 0, 0);
  acc[0][6] = __builtin_amdgcn_mfma_f32_16x16x32_bf16(a0, st.b6, acc[0][6], 0, 0, 0);
  acc[1][6] = __builtin_amdgcn_mfma_f32_16x16x32_bf16(a1, st.b6, acc[1][6], 0, 0, 0);
  acc[0][7] = __builtin_amdgcn_mfma_f32_16x16x32_bf16(a0, st.b7, acc[0][7], 0, 0, 0);
  acc[1][7] = __builtin_amdgcn_mfma_f32_16x16x32_bf16(a1, st.b7, acc[1][7], 0, 0, 0);
}

__global__ __launch_bounds__(256, 2) void hash_bits_kernel(
    const float* __restrict__ A, int M,
    const unsigned short* __restrict__ Wb,
    const float* __restrict__ hb,
    uint32_t* __restrict__ out_bits) {
  const int t    = threadIdx.x;
  const int lane = t & 63;
  const int w    = t >> 6;
  const int l15  = lane & 15;
  const int kg   = lane >> 4;           // k-group 0..3
  const int bm0  = blockIdx.x * 128;
  const int wrow = w * 32;              // block-local first row of this wave

  int ar0 = bm0 + wrow + l15;
  int ar1 = ar0 + 16;
  if (ar0 > M - 1) ar0 = M - 1;         // tail clamp (stores are guarded)
  if (ar1 > M - 1) ar1 = M - 1;

  const float* pa0 = A + (size_t)ar0 * KDIM + kg * 8;
  const float* pa1 = A + (size_t)ar1 * KDIM + kg * 8;
  const unsigned short* pb = Wb + (size_t)l15 * KDIM + kg * 8;

  f32x4 acc[2][8];
#pragma unroll
  for (int i = 0; i < 2; ++i)
#pragma unroll
    for (int j = 0; j < 8; ++j) acc[i][j] = (f32x4){0.f, 0.f, 0.f, 0.f};

  Stage sA, sB;
  ldstage(sA, pa0, pa1, pb, 0);
  for (int kt = 0; kt < KDIM; kt += 64) {
    ldstage(sB, pa0, pa1, pb, kt + 32);
    compute(sA, acc);
    if (kt + 64 < KDIM) ldstage(sA, pa0, pa1, pb, kt + 64);
    compute(sB, acc);
  }

  // ---- epilogue: sign + ballot-pack 128-bit codes, no LDS ----
  float hbv[8];
#pragma unroll
  for (int j = 0; j < 8; ++j) hbv[j] = hb[j * 16 + l15];

  const int g = lane >> 4;      // row-group within ballot
  const int q = lane & 15;      // word selector (q<4 writes)
#pragma unroll
  for (int i = 0; i < 2; ++i) {
#pragma unroll
    for (int r = 0; r < 4; ++r) {
      uint64_t b0 = __ballot(acc[i][0][r] + hbv[0] - 0.5f > 0.f);
      uint64_t b1 = __ballot(acc[i][1][r] + hbv[1] - 0.5f > 0.f);
      uint64_t b2 = __ballot(acc[i][2][r] + hbv[2] - 0.5f > 0.f);
      uint64_t b3 = __ballot(acc[i][3][r] + hbv[3] - 0.5f > 0.f);
      uint64_t b4 = __ballot(acc[i][4][r] + hbv[4] - 0.5f > 0.f);
      uint64_t b5 = __ballot(acc[i][5][r] + hbv[5] - 0.5f > 0.f);
      uint64_t b6 = __ballot(acc[i][6][r] + hbv[6] - 0.5f > 0.f);
      uint64_t b7 = __ballot(acc[i][7][r] + hbv[7] - 0.5f > 0.f);
      uint32_t w0 = (uint32_t)((b0 >> (16 * g)) & 0xFFFF) | ((uint32_t)((b1 >> (16 * g)) & 0xFFFF) << 16);
      uint32_t w1 = (uint32_t)((b2 >> (16 * g)) & 0xFFFF) | ((uint32_t)((b3 >> (16 * g)) & 0xFFFF) << 16);
      uint32_t w2 = (uint32_t)((b4 >> (16 * g)) & 0xFFFF) | ((uint32_t)((b5 >> (16 * g)) & 0xFFFF) << 16);
      uint32_t w3 = (uint32_t)((b6 >> (16 * g)) & 0xFFFF) | ((uint32_t)((b7 >> (16 * g)) & 0xFFFF) << 16);
      int grow = bm0 + wrow + i * 16 + 4 * g + r;
      if (q < 4 && grow < M) {
        uint32_t word = (q == 0) ? w0 : (q == 1) ? w1 : (q == 2) ? w2 : w3;
        out_bits[(size_t)grow * 4 + q] = word;
      }
    }
  }
}

// ---- Kernel hf: fp32 feature codes (must stay f32 — tiny margins) ----------
__global__ __launch_bounds__(64) void hf_kernel(
    const float* __restrict__ flat, const float* __restrict__ W,
    const float* __restrict__ hb, unsigned char* __restrict__ hf_bytes) {
  int bid = blockIdx.x;            // 8192 = 64 b * 128 n
  int n = bid & 127, b = bid >> 7;
  int lane = threadIdx.x;
  const f32x4* fa = reinterpret_cast<const f32x4*>(flat + (size_t)b * KDIM);
  const f32x4* wa = reinterpret_cast<const f32x4*>(W + (size_t)n * KDIM);
  float s = 0.f;
#pragma unroll 4
  for (int q = 0; q < 16; ++q) {
    f32x4 x = fa[lane + 64 * q], y = wa[lane + 64 * q];
    s += x[0] * y[0] + x[1] * y[1] + x[2] * y[2] + x[3] * y[3];
  }
  for (int o = 32; o; o >>= 1) s += __shfl_down(s, o, 64);
  if (lane == 0) hf_bytes[b * NH + n] = (s + hb[n] - 0.5f) > 0.f ? 1 : 0;
}

// ---- Kernel B: per-batch argmin Hamming (ref tie-break) + fused gather ------
__global__ __launch_bounds__(256) void argmin_gather_kernel(
    const uint32_t* __restrict__ hm_bits, const unsigned char* __restrict__ hf_bytes,
    const float* __restrict__ memory, int M, float* __restrict__ out) {
  __shared__ uint32_t red[256];
  const int b = blockIdx.x;
  const int t = threadIdx.x;
  uint64_t hf0 = 0, hf1 = 0;
  const unsigned char* hfb = hf_bytes + b * NH;
  for (int c = 0; c < 64; ++c) {
    hf0 |= (uint64_t)(hfb[c] & 1u) << c;
    hf1 |= (uint64_t)(hfb[c + 64] & 1u) << c;
  }
  int hfsum = __popcll(hf0) + __popcll(hf1);
  uint32_t best = 0xFFFFFFFFu;
  for (int m = t; m < M; m += 256) {
    u32x4 pv = reinterpret_cast<const u32x4*>(hm_bits)[m];
    uint64_t h0 = (uint64_t)pv[0] | ((uint64_t)pv[1] << 32);
    uint64_t h1 = (uint64_t)pv[2] | ((uint64_t)pv[3] << 32);
    int hmsum = __popcll(h0) + __popcll(h1);
    int dot   = __popcll(h0 & hf0) + __popcll(h1 & hf1);
    int hd    = hfsum + hmsum - 2 * dot;
    uint32_t key = ((uint32_t)hd << 16) | (uint32_t)m;   // M < 65536, HD <= 256
    best = best < key ? best : key;
  }
  red[t] = best;
  __syncthreads();
  for (int s = 128; s > 0; s >>= 1) {
    if (t < s) red[t] = red[t] < red[t + s] ? red[t] : red[t + s];
    __syncthreads();
  }
  int m = (int)(red[0] & 0xFFFFu);
  const f32x4* src = reinterpret_cast<const f32x4*>(memory + (size_t)m * KDIM);
  f32x4* dst = reinterpret_cast<f32x4*>(out + (size_t)b * KDIM);
#pragma unroll
  for (int c = 0; c < 4; ++c) dst[t + 256 * c] = src[t + 256 * c];
}

extern "C" void kernel_launch(void* const* d_in, const int* in_sizes, int n_in,
                              void* d_out, int out_size, void* d_ws, size_t ws_size,
                              hipStream_t stream) {
  const float* feature = (const float*)d_in[0];   // [64,64,8,8] == [64,4096]
  const float* memory  = (const float*)d_in[1];   // [50000,4096]
  const float* hash_W  = (const float*)d_in[2];   // [128,4096]
  const float* hash_b  = (const float*)d_in[3];   // [128]
  float* out = (float*)d_out;

  char* ws = (char*)d_ws;
  unsigned short* Wb       = (unsigned short*)ws;                       // 1,048,576 B
  uint32_t*       hm_bits  = (uint32_t*)(ws + 1048576);                 //   800,000 B
  unsigned char*  hf_bytes = (unsigned char*)(ws + 1048576 + 800000);   //     8,192 B

  convert_w_kernel<<<(NH * KDIM / 4) / 256, 256, 0, stream>>>(hash_W, Wb);
  hash_bits_kernel<<<(MMEM + 127) / 128, 256, 0, stream>>>(memory, MMEM, Wb, hash_b, hm_bits);
  hf_kernel<<<BFEAT * NH, 64, 0, stream>>>(feature, hash_W, hash_b, hf_bytes);
  argmin_gather_kernel<<<BFEAT, 256, 0, stream>>>(hm_bits, hf_bytes, memory, MMEM, out);
}

// Round 3
// 257.807 us; speedup vs baseline: 1.7478x; 1.7478x over previous
//
#include <hip/hip_runtime.h>
#include <hip/hip_bf16.h>
#include <stdint.h>
#include <stddef.h>

typedef __attribute__((ext_vector_type(8))) short s8v;       // 8 x bf16 (as i16)
typedef __attribute__((ext_vector_type(4))) float f32x4;
typedef __attribute__((ext_vector_type(4))) uint32_t u32x4;
typedef __attribute__((ext_vector_type(4))) unsigned short u16x4;

#define KDIM 4096
#define NH   128
#define MMEM 50000
#define BFEAT 64
#define KCH  64                 // K per LDS chunk
#define NCH  (KDIM / KCH)       // 64 chunks
#define BM   64                 // rows per block (4 waves x 16)
#define NSEG 8                  // argmin M-segments

static __device__ __forceinline__ unsigned short f2bf(float f) {
  union { float f; uint32_t u; } c; c.f = f;
  uint32_t u = c.u;
  return (unsigned short)((u + 0x7FFFu + ((u >> 16) & 1u)) >> 16);  // RNE
}

static __device__ __forceinline__ short f2bfs(float f) {
  __hip_bfloat16 h = __float2bfloat16(f);   // pairs fuse to v_cvt_pk_bf16_f32
  short s;
  __builtin_memcpy(&s, &h, sizeof(s));
  return s;
}

static __device__ __forceinline__ void gload16(const void* g, void* l) {
  __builtin_amdgcn_global_load_lds(
      (const __attribute__((address_space(1))) unsigned int*)g,
      (__attribute__((address_space(3))) unsigned int*)l, 16, 0, 0);
}

// ---- Kernel 0: hash_W f32 -> bf16, plus argmin-key init ---------------------
__global__ __launch_bounds__(256) void convert_w_kernel(
    const float* __restrict__ W, unsigned short* __restrict__ Wb,
    unsigned int* __restrict__ keys) {
  int i = blockIdx.x * 256 + threadIdx.x;          // float4 index, 131072 total
  if (blockIdx.x == 0 && threadIdx.x < BFEAT) keys[threadIdx.x] = 0xFFFFFFFFu;
  f32x4 v = reinterpret_cast<const f32x4*>(W)[i];
  u16x4 o;
  o[0] = f2bf(v[0]); o[1] = f2bf(v[1]); o[2] = f2bf(v[2]); o[3] = f2bf(v[3]);
  reinterpret_cast<u16x4*>(Wb)[i] = o;
}

// ---- Kernel A: streaming bf16 MFMA; A direct-to-reg, B LDS via gload_lds ----
// Wave owns 16 rows x 128 cols. B chunk [128 rows][64 k] bf16 = 16KB, dbuf.
// LDS swizzle: 16B-granule g' = g ^ (row&7); DMA dest linear, source
// inverse-swizzled, read swizzled (both-sides rule).

static __device__ __forceinline__ void stageB(
    unsigned short* bufBase, const unsigned short* __restrict__ Wb,
    int kt, int t, int w) {
#pragma unroll
  for (int c = 0; c < 4; ++c) {
    int idx = t + 256 * c;            // granule 0..1023
    int row = idx >> 3;
    int gs  = idx & 7;
    const unsigned short* src = Wb + (size_t)row * KDIM + kt + ((gs ^ (row & 7)) << 3);
    unsigned short* dst = bufBase + ((size_t)(w * 64 + 256 * c) << 3);  // wave-uniform
    gload16(src, dst);
  }
}

static __device__ __forceinline__ void issueA(
    f32x4 (&ar)[4], const float* pa0, int kt) {
#pragma unroll
  for (int s = 0; s < 2; ++s) {
    const f32x4* q = reinterpret_cast<const f32x4*>(pa0 + kt + s * 32);
    ar[s * 2 + 0] = q[0];
    ar[s * 2 + 1] = q[1];
  }
}

static __device__ __forceinline__ void chunkCompute(
    const unsigned short* bufBase, int l15, int kg,
    const f32x4 (&ar)[4], f32x4 (&acc)[8]) {
#pragma unroll
  for (int s = 0; s < 2; ++s) {
    s8v a0;
#pragma unroll
    for (int q = 0; q < 4; ++q) {
      a0[q]     = f2bfs(ar[s * 2 + 0][q]);
      a0[q + 4] = f2bfs(ar[s * 2 + 1][q]);
    }
#pragma unroll
    for (int j = 0; j < 8; ++j) {
      int row = j * 16 + l15;
      int gr  = (s * 4 + kg) ^ (row & 7);
      const s8v bf = *reinterpret_cast<const s8v*>(bufBase + ((row * 8 + gr) << 3));
      acc[j] = __builtin_amdgcn_mfma_f32_16x16x32_bf16(a0, bf, acc[j], 0, 0, 0);
    }
  }
}

__global__ __launch_bounds__(256, 3) void hash_bits_kernel(
    const float* __restrict__ A, int M,
    const unsigned short* __restrict__ Wb,
    const float* __restrict__ hb,
    uint32_t* __restrict__ out_bits) {
  __shared__ unsigned short Bs[2][NH * KCH];   // 2 x 16 KB

  const int t    = threadIdx.x;
  const int lane = t & 63;
  const int w    = t >> 6;
  const int l15  = lane & 15;
  const int kg   = lane >> 4;
  const int bm0  = blockIdx.x * BM;

  int ar0 = bm0 + w * 16 + l15;
  if (ar0 > M - 1) ar0 = M - 1;            // tail clamp; stores guarded
  const float* pa0 = A + (size_t)ar0 * KDIM + kg * 8;

  f32x4 acc[8];
#pragma unroll
  for (int j = 0; j < 8; ++j) acc[j] = (f32x4){0.f, 0.f, 0.f, 0.f};

  f32x4 aA[4], aB[4];

  stageB(&Bs[0][0], Wb, 0, t, w);
  issueA(aA, pa0, 0);
  __syncthreads();

  for (int c = 0; c < NCH; c += 2) {
    if (c + 1 < NCH) {                     // prefetch chunk c+1 (early issue)
      stageB(&Bs[1][0], Wb, (c + 1) * KCH, t, w);
      issueA(aB, pa0, (c + 1) * KCH);
    }
    chunkCompute(&Bs[0][0], l15, kg, aA, acc);
    __syncthreads();                       // drain is ~free: issued a chunk ago
    if (c + 2 < NCH) {
      stageB(&Bs[0][0], Wb, (c + 2) * KCH, t, w);
      issueA(aA, pa0, (c + 2) * KCH);
    }
    chunkCompute(&Bs[1][0], l15, kg, aB, acc);
    __syncthreads();
  }

  // ---- epilogue: sign + ballot-pack 128-bit codes ----
  float hbv[8];
#pragma unroll
  for (int j = 0; j < 8; ++j) hbv[j] = hb[j * 16 + l15];
  const int q = lane & 15;
#pragma unroll
  for (int r = 0; r < 4; ++r) {
    uint64_t b0 = __ballot(acc[0][r] + hbv[0] - 0.5f > 0.f);
    uint64_t b1 = __ballot(acc[1][r] + hbv[1] - 0.5f > 0.f);
    uint64_t b2 = __ballot(acc[2][r] + hbv[2] - 0.5f > 0.f);
    uint64_t b3 = __ballot(acc[3][r] + hbv[3] - 0.5f > 0.f);
    uint64_t b4 = __ballot(acc[4][r] + hbv[4] - 0.5f > 0.f);
    uint64_t b5 = __ballot(acc[5][r] + hbv[5] - 0.5f > 0.f);
    uint64_t b6 = __ballot(acc[6][r] + hbv[6] - 0.5f > 0.f);
    uint64_t b7 = __ballot(acc[7][r] + hbv[7] - 0.5f > 0.f);
    uint32_t w0 = (uint32_t)((b0 >> (16 * kg)) & 0xFFFF) | ((uint32_t)((b1 >> (16 * kg)) & 0xFFFF) << 16);
    uint32_t w1 = (uint32_t)((b2 >> (16 * kg)) & 0xFFFF) | ((uint32_t)((b3 >> (16 * kg)) & 0xFFFF) << 16);
    uint32_t w2 = (uint32_t)((b4 >> (16 * kg)) & 0xFFFF) | ((uint32_t)((b5 >> (16 * kg)) & 0xFFFF) << 16);
    uint32_t w3 = (uint32_t)((b6 >> (16 * kg)) & 0xFFFF) | ((uint32_t)((b7 >> (16 * kg)) & 0xFFFF) << 16);
    int grow = bm0 + w * 16 + 4 * kg + r;
    if (q < 4 && grow < M) {
      uint32_t word = (q == 0) ? w0 : (q == 1) ? w1 : (q == 2) ? w2 : w3;
      out_bits[(size_t)grow * 4 + q] = word;
    }
  }
}

// ---- Kernel hf: fp32 feature codes (tiny margins -> stay f32) ---------------
__global__ __launch_bounds__(64) void hf_kernel(
    const float* __restrict__ flat, const float* __restrict__ W,
    const float* __restrict__ hb, unsigned char* __restrict__ hf_bytes) {
  int bid = blockIdx.x;            // 8192 = 64 b * 128 n
  int n = bid & 127, b = bid >> 7;
  int lane = threadIdx.x;
  const f32x4* fa = reinterpret_cast<const f32x4*>(flat + (size_t)b * KDIM);
  const f32x4* wa = reinterpret_cast<const f32x4*>(W + (size_t)n * KDIM);
  float s = 0.f;
#pragma unroll 4
  for (int q = 0; q < 16; ++q) {
    f32x4 x = fa[lane + 64 * q], y = wa[lane + 64 * q];
    s += x[0] * y[0] + x[1] * y[1] + x[2] * y[2] + x[3] * y[3];
  }
  for (int o = 32; o; o >>= 1) s += __shfl_down(s, o, 64);
  if (lane == 0) hf_bytes[b * NH + n] = (s + hb[n] - 0.5f) > 0.f ? 1 : 0;
}

// ---- Kernel B: segmented argmin Hamming (ref tie-break) via atomicMin -------
__global__ __launch_bounds__(256) void argmin_part_kernel(
    const uint32_t* __restrict__ hm_bits, const unsigned char* __restrict__ hf_bytes,
    int M, unsigned int* __restrict__ keys) {
  __shared__ uint32_t red[256];
  const int b   = blockIdx.x & (BFEAT - 1);
  const int seg = blockIdx.x / BFEAT;
  const int span = (M + NSEG - 1) / NSEG;
  const int m0 = seg * span;
  int m1 = m0 + span; if (m1 > M) m1 = M;
  const int t = threadIdx.x;
  uint64_t hf0 = 0, hf1 = 0;
  const unsigned char* hfb = hf_bytes + b * NH;
  for (int c = 0; c < 64; ++c) {
    hf0 |= (uint64_t)(hfb[c] & 1u) << c;
    hf1 |= (uint64_t)(hfb[c + 64] & 1u) << c;
  }
  int hfsum = __popcll(hf0) + __popcll(hf1);
  uint32_t best = 0xFFFFFFFFu;
  for (int m = m0 + t; m < m1; m += 256) {
    u32x4 pv = reinterpret_cast<const u32x4*>(hm_bits)[m];
    uint64_t h0 = (uint64_t)pv[0] | ((uint64_t)pv[1] << 32);
    uint64_t h1 = (uint64_t)pv[2] | ((uint64_t)pv[3] << 32);
    int hmsum = __popcll(h0) + __popcll(h1);
    int dot   = __popcll(h0 & hf0) + __popcll(h1 & hf1);
    int hd    = hfsum + hmsum - 2 * dot;
    uint32_t key = ((uint32_t)hd << 16) | (uint32_t)m;   // M < 65536, HD <= 256
    best = best < key ? best : key;
  }
  red[t] = best;
  __syncthreads();
  for (int s = 128; s > 0; s >>= 1) {
    if (t < s) red[t] = red[t] < red[t + s] ? red[t] : red[t + s];
    __syncthreads();
  }
  if (t == 0) atomicMin(&keys[b], red[0]);   // device-scope, order-independent
}

// ---- Kernel C: gather nearest memory rows -----------------------------------
__global__ __launch_bounds__(256) void gather_kernel(
    const float* __restrict__ memory, const unsigned int* __restrict__ keys,
    float* __restrict__ out) {
  int b = blockIdx.x;
  int t = threadIdx.x;
  int m = (int)(keys[b] & 0xFFFFu);
  const f32x4* src = reinterpret_cast<const f32x4*>(memory + (size_t)m * KDIM);
  f32x4* dst = reinterpret_cast<f32x4*>(out + (size_t)b * KDIM);
#pragma unroll
  for (int c = 0; c < 4; ++c) dst[t + 256 * c] = src[t + 256 * c];
}

extern "C" void kernel_launch(void* const* d_in, const int* in_sizes, int n_in,
                              void* d_out, int out_size, void* d_ws, size_t ws_size,
                              hipStream_t stream) {
  const float* feature = (const float*)d_in[0];   // [64,64,8,8] == [64,4096]
  const float* memory  = (const float*)d_in[1];   // [50000,4096]
  const float* hash_W  = (const float*)d_in[2];   // [128,4096]
  const float* hash_b  = (const float*)d_in[3];   // [128]
  float* out = (float*)d_out;

  char* ws = (char*)d_ws;
  unsigned short* Wb       = (unsigned short*)ws;                       // 1,048,576 B
  uint32_t*       hm_bits  = (uint32_t*)(ws + 1048576);                 //   800,000 B
  unsigned char*  hf_bytes = (unsigned char*)(ws + 1048576 + 800000);   //     8,192 B
  unsigned int*   keys     = (unsigned int*)(ws + 1048576 + 800000 + 8192); //   256 B

  convert_w_kernel<<<(NH * KDIM / 4) / 256, 256, 0, stream>>>(hash_W, Wb, keys);
  hash_bits_kernel<<<(MMEM + BM - 1) / BM, 256, 0, stream>>>(memory, MMEM, Wb, hash_b, hm_bits);
  hf_kernel<<<BFEAT * NH, 64, 0, stream>>>(feature, hash_W, hash_b, hf_bytes);
  argmin_part_kernel<<<BFEAT * NSEG, 256, 0, stream>>>(hm_bits, hf_bytes, MMEM, keys);
  gather_kernel<<<BFEAT, 256, 0, stream>>>(memory, keys, out);
}

// Round 4
// 235.515 us; speedup vs baseline: 1.9132x; 1.0947x over previous
//
#include <hip/hip_runtime.h>
#include <hip/hip_bf16.h>
#include <stdint.h>
#include <stddef.h>

typedef __attribute__((ext_vector_type(8))) short s8v;       // 8 x bf16 (as i16)
typedef __attribute__((ext_vector_type(4))) float f32x4;
typedef __attribute__((ext_vector_type(4))) uint32_t u32x4;
typedef __attribute__((ext_vector_type(4))) unsigned short u16x4;

#define KDIM 4096
#define NH   128
#define MMEM 50000
#define BFEAT 64
#define KCH  64                 // K per LDS chunk
#define NCH  (KDIM / KCH)       // 64 chunks
#define BM   128                // rows per block (4 waves x 32)
#define NSEG 8                  // argmin M-segments

static __device__ __forceinline__ unsigned short f2bf(float f) {
  union { float f; uint32_t u; } c; c.f = f;
  uint32_t u = c.u;
  return (unsigned short)((u + 0x7FFFu + ((u >> 16) & 1u)) >> 16);  // RNE
}

static __device__ __forceinline__ short f2bfs(float f) {
  __hip_bfloat16 h = __float2bfloat16(f);   // pairs fuse to v_cvt_pk_bf16_f32
  short s;
  __builtin_memcpy(&s, &h, sizeof(s));
  return s;
}

static __device__ __forceinline__ void gload16(const void* g, void* l) {
  __builtin_amdgcn_global_load_lds(
      (const __attribute__((address_space(1))) unsigned int*)g,
      (__attribute__((address_space(3))) unsigned int*)l, 16, 0, 0);
}

// ---- Kernel 0: hash_W f32 -> bf16, plus argmin-key init ---------------------
__global__ __launch_bounds__(256) void convert_w_kernel(
    const float* __restrict__ W, unsigned short* __restrict__ Wb,
    unsigned int* __restrict__ keys) {
  int i = blockIdx.x * 256 + threadIdx.x;          // float4 index, 131072 total
  if (blockIdx.x == 0 && threadIdx.x < BFEAT) keys[threadIdx.x] = 0xFFFFFFFFu;
  f32x4 v = reinterpret_cast<const f32x4*>(W)[i];
  u16x4 o;
  o[0] = f2bf(v[0]); o[1] = f2bf(v[1]); o[2] = f2bf(v[2]); o[3] = f2bf(v[3]);
  reinterpret_cast<u16x4*>(Wb)[i] = o;
}

// ---- Kernel A: streaming bf16 MFMA; counted-vmcnt pipeline ------------------
// Wave owns 32 rows x 128 cols. B chunk [128 rows][64 k] bf16 = 16KB, 4-deep
// ring staged via global_load_lds 3 chunks ahead; A regs 2 chunks ahead.
// Raw s_barrier + exact vmcnt counts (issue order pinned by sched_barrier).

static __device__ __forceinline__ void stageB(
    unsigned short* bufBase, const unsigned short* __restrict__ Wb,
    int kt, int t, int w) {
#pragma unroll
  for (int c = 0; c < 4; ++c) {
    int idx = t + 256 * c;            // granule 0..1023
    int row = idx >> 3;
    int gs  = idx & 7;
    const unsigned short* src = Wb + (size_t)row * KDIM + kt + ((gs ^ (row & 7)) << 3);
    unsigned short* dst = bufBase + ((size_t)(w * 64 + 256 * c) << 3);  // wave-uniform
    gload16(src, dst);
  }
}

static __device__ __forceinline__ void issueA(
    f32x4 (&ar)[8], const float* pa0, const float* pa1, int kt) {
#pragma unroll
  for (int s = 0; s < 2; ++s) {
    const f32x4* q0 = reinterpret_cast<const f32x4*>(pa0 + kt + s * 32);
    ar[s * 2 + 0] = q0[0];
    ar[s * 2 + 1] = q0[1];
    const f32x4* q1 = reinterpret_cast<const f32x4*>(pa1 + kt + s * 32);
    ar[4 + s * 2 + 0] = q1[0];
    ar[4 + s * 2 + 1] = q1[1];
  }
}

static __device__ __forceinline__ void chunkCompute(
    const unsigned short* bufBase, int l15, int kg,
    const f32x4 (&ar)[8], f32x4 (&acc)[2][8]) {
#pragma unroll
  for (int s = 0; s < 2; ++s) {
    s8v a0, a1;
#pragma unroll
    for (int q = 0; q < 4; ++q) {
      a0[q]     = f2bfs(ar[s * 2 + 0][q]);
      a0[q + 4] = f2bfs(ar[s * 2 + 1][q]);
      a1[q]     = f2bfs(ar[4 + s * 2 + 0][q]);
      a1[q + 4] = f2bfs(ar[4 + s * 2 + 1][q]);
    }
#pragma unroll
    for (int j = 0; j < 8; ++j) {
      int row = j * 16 + l15;
      int gr  = (s * 4 + kg) ^ (row & 7);
      const s8v bf = *reinterpret_cast<const s8v*>(bufBase + ((row * 8 + gr) << 3));
      acc[0][j] = __builtin_amdgcn_mfma_f32_16x16x32_bf16(a0, bf, acc[0][j], 0, 0, 0);
      acc[1][j] = __builtin_amdgcn_mfma_f32_16x16x32_bf16(a1, bf, acc[1][j], 0, 0, 0);
    }
  }
}

// One pipeline sub-step for chunk CN (buffer B4 = CN&3).
// Order: wait+barrier | issue A(CN+2) | issue DMA(CN+3) | compute CN.
// vmcnt counts: per chunk 8 A-loads + 4 DMA; see derivation in commit note.
#define PIPE_STEP(B4, CNT, CN, DO_A, DO_D) do {                               \
  asm volatile("s_waitcnt vmcnt(" #CNT ")" ::: "memory");                     \
  __builtin_amdgcn_s_barrier();                                               \
  __builtin_amdgcn_sched_barrier(0);                                          \
  if (DO_A) {                                                                 \
    issueA(aR[((B4) + 2) & 3], pa0, pa1, ((CN) + 2) * KCH);                   \
    __builtin_amdgcn_sched_barrier(0);                                        \
  }                                                                           \
  if (DO_D) {                                                                 \
    stageB(&Bs[((B4) + 3) & 3][0], Wb, ((CN) + 3) * KCH, t, w);               \
    __builtin_amdgcn_sched_barrier(0);                                        \
  }                                                                           \
  chunkCompute(&Bs[B4][0], l15, kg, aR[B4], acc);                             \
} while (0)

__global__ __launch_bounds__(256, 2) void hash_bits_kernel(
    const float* __restrict__ A, int M,
    const unsigned short* __restrict__ Wb,
    const float* __restrict__ hb,
    uint32_t* __restrict__ out_bits) {
  __shared__ unsigned short Bs[4][NH * KCH];   // 4 x 16 KB ring

  const int t    = threadIdx.x;
  const int lane = t & 63;
  const int w    = t >> 6;
  const int l15  = lane & 15;
  const int kg   = lane >> 4;
  const int bm0  = blockIdx.x * BM;
  const int wrow = w * 32;

  int ar0 = bm0 + wrow + l15;
  int ar1 = ar0 + 16;
  if (ar0 > M - 1) ar0 = M - 1;            // tail clamp; stores guarded
  if (ar1 > M - 1) ar1 = M - 1;
  const float* pa0 = A + (size_t)ar0 * KDIM + kg * 8;
  const float* pa1 = A + (size_t)ar1 * KDIM + kg * 8;

  f32x4 acc[2][8];
#pragma unroll
  for (int i = 0; i < 2; ++i)
#pragma unroll
    for (int j = 0; j < 8; ++j) acc[i][j] = (f32x4){0.f, 0.f, 0.f, 0.f};

  f32x4 aR[4][8];   // A-reg ring, all indices compile-time constant

  // Prologue: DMA(0), A(0), DMA(1), A(1), DMA(2) — matches steady-state counts
  stageB(&Bs[0][0], Wb, 0, t, w);
  __builtin_amdgcn_sched_barrier(0);
  issueA(aR[0], pa0, pa1, 0);
  __builtin_amdgcn_sched_barrier(0);
  stageB(&Bs[1][0], Wb, 1 * KCH, t, w);
  __builtin_amdgcn_sched_barrier(0);
  issueA(aR[1], pa0, pa1, 1 * KCH);
  __builtin_amdgcn_sched_barrier(0);
  stageB(&Bs[2][0], Wb, 2 * KCH, t, w);
  __builtin_amdgcn_sched_barrier(0);

  for (int c = 0; c < NCH - 4; c += 4) {
    PIPE_STEP(0, 24, c + 0, 1, 1);
    PIPE_STEP(1, 24, c + 1, 1, 1);
    PIPE_STEP(2, 24, c + 2, 1, 1);
    PIPE_STEP(3, 24, c + 3, 1, 1);
  }
  // Tail: chunks 60..63 (A issue while CN+2<=63, DMA while CN+3<=63)
  PIPE_STEP(0, 24, 60, 1, 1);
  PIPE_STEP(1, 24, 61, 1, 0);
  PIPE_STEP(2, 20, 62, 0, 0);
  PIPE_STEP(3, 8,  63, 0, 0);

  // ---- epilogue: sign + ballot-pack 128-bit codes (validated R2) ----
  float hbv[8];
#pragma unroll
  for (int j = 0; j < 8; ++j) hbv[j] = hb[j * 16 + l15];

  const int g = lane >> 4;      // row-group within ballot
  const int q = lane & 15;      // word selector (q<4 writes)
#pragma unroll
  for (int i = 0; i < 2; ++i) {
#pragma unroll
    for (int r = 0; r < 4; ++r) {
      uint64_t b0 = __ballot(acc[i][0][r] + hbv[0] - 0.5f > 0.f);
      uint64_t b1 = __ballot(acc[i][1][r] + hbv[1] - 0.5f > 0.f);
      uint64_t b2 = __ballot(acc[i][2][r] + hbv[2] - 0.5f > 0.f);
      uint64_t b3 = __ballot(acc[i][3][r] + hbv[3] - 0.5f > 0.f);
      uint64_t b4 = __ballot(acc[i][4][r] + hbv[4] - 0.5f > 0.f);
      uint64_t b5 = __ballot(acc[i][5][r] + hbv[5] - 0.5f > 0.f);
      uint64_t b6 = __ballot(acc[i][6][r] + hbv[6] - 0.5f > 0.f);
      uint64_t b7 = __ballot(acc[i][7][r] + hbv[7] - 0.5f > 0.f);
      uint32_t w0 = (uint32_t)((b0 >> (16 * g)) & 0xFFFF) | ((uint32_t)((b1 >> (16 * g)) & 0xFFFF) << 16);
      uint32_t w1 = (uint32_t)((b2 >> (16 * g)) & 0xFFFF) | ((uint32_t)((b3 >> (16 * g)) & 0xFFFF) << 16);
      uint32_t w2 = (uint32_t)((b4 >> (16 * g)) & 0xFFFF) | ((uint32_t)((b5 >> (16 * g)) & 0xFFFF) << 16);
      uint32_t w3 = (uint32_t)((b6 >> (16 * g)) & 0xFFFF) | ((uint32_t)((b7 >> (16 * g)) & 0xFFFF) << 16);
      int grow = bm0 + wrow + i * 16 + 4 * g + r;
      if (q < 4 && grow < M) {
        uint32_t word = (q == 0) ? w0 : (q == 1) ? w1 : (q == 2) ? w2 : w3;
        out_bits[(size_t)grow * 4 + q] = word;
      }
    }
  }
}

// ---- Kernel hf: fp32 feature codes (tiny margins -> stay f32) ---------------
__global__ __launch_bounds__(64) void hf_kernel(
    const float* __restrict__ flat, const float* __restrict__ W,
    const float* __restrict__ hb, unsigned char* __restrict__ hf_bytes) {
  int bid = blockIdx.x;            // 8192 = 64 b * 128 n
  int n = bid & 127, b = bid >> 7;
  int lane = threadIdx.x;
  const f32x4* fa = reinterpret_cast<const f32x4*>(flat + (size_t)b * KDIM);
  const f32x4* wa = reinterpret_cast<const f32x4*>(W + (size_t)n * KDIM);
  float s = 0.f;
#pragma unroll 4
  for (int q = 0; q < 16; ++q) {
    f32x4 x = fa[lane + 64 * q], y = wa[lane + 64 * q];
    s += x[0] * y[0] + x[1] * y[1] + x[2] * y[2] + x[3] * y[3];
  }
  for (int o = 32; o; o >>= 1) s += __shfl_down(s, o, 64);
  if (lane == 0) hf_bytes[b * NH + n] = (s + hb[n] - 0.5f) > 0.f ? 1 : 0;
}

// ---- Kernel B: segmented argmin Hamming (ref tie-break) via atomicMin -------
__global__ __launch_bounds__(256) void argmin_part_kernel(
    const uint32_t* __restrict__ hm_bits, const unsigned char* __restrict__ hf_bytes,
    int M, unsigned int* __restrict__ keys) {
  __shared__ uint32_t red[256];
  const int b   = blockIdx.x & (BFEAT - 1);
  const int seg = blockIdx.x / BFEAT;
  const int span = (M + NSEG - 1) / NSEG;
  const int m0 = seg * span;
  int m1 = m0 + span; if (m1 > M) m1 = M;
  const int t = threadIdx.x;
  uint64_t hf0 = 0, hf1 = 0;
  const unsigned char* hfb = hf_bytes + b * NH;
  for (int c = 0; c < 64; ++c) {
    hf0 |= (uint64_t)(hfb[c] & 1u) << c;
    hf1 |= (uint64_t)(hfb[c + 64] & 1u) << c;
  }
  int hfsum = __popcll(hf0) + __popcll(hf1);
  uint32_t best = 0xFFFFFFFFu;
  for (int m = m0 + t; m < m1; m += 256) {
    u32x4 pv = reinterpret_cast<const u32x4*>(hm_bits)[m];
    uint64_t h0 = (uint64_t)pv[0] | ((uint64_t)pv[1] << 32);
    uint64_t h1 = (uint64_t)pv[2] | ((uint64_t)pv[3] << 32);
    int hmsum = __popcll(h0) + __popcll(h1);
    int dot   = __popcll(h0 & hf0) + __popcll(h1 & hf1);
    int hd    = hfsum + hmsum - 2 * dot;
    uint32_t key = ((uint32_t)hd << 16) | (uint32_t)m;   // M < 65536, HD <= 256
    best = best < key ? best : key;
  }
  red[t] = best;
  __syncthreads();
  for (int s = 128; s > 0; s >>= 1) {
    if (t < s) red[t] = red[t] < red[t + s] ? red[t] : red[t + s];
    __syncthreads();
  }
  if (t == 0) atomicMin(&keys[b], red[0]);   // device-scope, order-independent
}

// ---- Kernel C: gather nearest memory rows -----------------------------------
__global__ __launch_bounds__(256) void gather_kernel(
    const float* __restrict__ memory, const unsigned int* __restrict__ keys,
    float* __restrict__ out) {
  int b = blockIdx.x;
  int t = threadIdx.x;
  int m = (int)(keys[b] & 0xFFFFu);
  const f32x4* src = reinterpret_cast<const f32x4*>(memory + (size_t)m * KDIM);
  f32x4* dst = reinterpret_cast<f32x4*>(out + (size_t)b * KDIM);
#pragma unroll
  for (int c = 0; c < 4; ++c) dst[t + 256 * c] = src[t + 256 * c];
}

extern "C" void kernel_launch(void* const* d_in, const int* in_sizes, int n_in,
                              void* d_out, int out_size, void* d_ws, size_t ws_size,
                              hipStream_t stream) {
  const float* feature = (const float*)d_in[0];   // [64,64,8,8] == [64,4096]
  const float* memory  = (const float*)d_in[1];   // [50000,4096]
  const float* hash_W  = (const float*)d_in[2];   // [128,4096]
  const float* hash_b  = (const float*)d_in[3];   // [128]
  float* out = (float*)d_out;

  char* ws = (char*)d_ws;
  unsigned short* Wb       = (unsigned short*)ws;                       // 1,048,576 B
  uint32_t*       hm_bits  = (uint32_t*)(ws + 1048576);                 //   800,000 B
  unsigned char*  hf_bytes = (unsigned char*)(ws + 1048576 + 800000);   //     8,192 B
  unsigned int*   keys     = (unsigned int*)(ws + 1048576 + 800000 + 8192); //   256 B

  convert_w_kernel<<<(NH * KDIM / 4) / 256, 256, 0, stream>>>(hash_W, Wb, keys);
  hash_bits_kernel<<<(MMEM + BM - 1) / BM, 256, 0, stream>>>(memory, MMEM, Wb, hash_b, hm_bits);
  hf_kernel<<<BFEAT * NH, 64, 0, stream>>>(feature, hash_W, hash_b, hf_bytes);
  argmin_part_kernel<<<BFEAT * NSEG, 256, 0, stream>>>(hm_bits, hf_bytes, MMEM, keys);
  gather_kernel<<<BFEAT, 256, 0, stream>>>(memory, keys, out);
}

// Round 5
// 191.042 us; speedup vs baseline: 2.3586x; 1.2328x over previous
//
#include <hip/hip_runtime.h>
#include <hip/hip_bf16.h>
#include <stdint.h>
#include <stddef.h>

typedef __attribute__((ext_vector_type(8))) short s8v;       // 8 x bf16 (as i16)
typedef __attribute__((ext_vector_type(4))) float f32x4;
typedef __attribute__((ext_vector_type(4))) uint32_t u32x4;
typedef __attribute__((ext_vector_type(4))) unsigned short u16x4;

#define KDIM 4096
#define NH   128
#define MMEM 50000
#define BFEAT 64
#define NGRP 3125               // 50000 / 16 row-groups, exact
#define NBLK 256                // one block per CU, perfect balance
#define NGMAX 13                // max groups per block (53 blocks have 13, rest 12)
#define NSEG 8                  // argmin M-segments

static __device__ __forceinline__ unsigned short f2bf(float f) {
  union { float f; uint32_t u; } c; c.f = f;
  uint32_t u = c.u;
  return (unsigned short)((u + 0x7FFFu + ((u >> 16) & 1u)) >> 16);  // RNE
}

static __device__ __forceinline__ short f2bfs(float f) {
  __hip_bfloat16 h = __float2bfloat16(f);   // pairs fuse to v_cvt_pk_bf16_f32
  short s;
  __builtin_memcpy(&s, &h, sizeof(s));
  return s;
}

// ---- Kernel 0: hash_W f32 -> bf16, plus argmin-key init ---------------------
__global__ __launch_bounds__(256) void convert_w_kernel(
    const float* __restrict__ W, unsigned short* __restrict__ Wb,
    unsigned int* __restrict__ keys) {
  int i = blockIdx.x * 256 + threadIdx.x;          // float4 index, 131072 total
  if (blockIdx.x == 0 && threadIdx.x < BFEAT) keys[threadIdx.x] = 0xFFFFFFFFu;
  f32x4 v = reinterpret_cast<const f32x4*>(W)[i];
  u16x4 o;
  o[0] = f2bf(v[0]); o[1] = f2bf(v[1]); o[2] = f2bf(v[2]); o[3] = f2bf(v[3]);
  reinterpret_cast<u16x4*>(Wb)[i] = o;
}

// ---- Kernel A: persistent balanced streaming MFMA ---------------------------
// 256 blocks x 512 threads. Block owns 12-13 groups of 16 memory rows, acc
// resident. K outer: per 64-k chunk all waves stage A (f32->bf16, swizzled
// LDS ring-2); waves own 16 cols each, B-frags reg-direct from L2.
// Sync: lgkmcnt(0)+raw s_barrier only (no vmcnt drain; compiler counts).

__global__ __launch_bounds__(512, 2) void hash_bits_kernel(
    const float* __restrict__ A,
    const unsigned short* __restrict__ Wb,
    const float* __restrict__ hb,
    uint32_t* __restrict__ out_bits) {
  __shared__ short Abuf[2][NGMAX * 16 * 64];       // 2 x 26 KB bf16, swizzled
  __shared__ unsigned short smb[NGMAX * 16][8];    // epilogue u16 slices

  const int t    = threadIdx.x;
  const int lane = t & 63;
  const int w    = t >> 6;          // wave 0..7 -> cols 16w..16w+15
  const int l15  = lane & 15;
  const int kq   = lane >> 4;
  const int b    = blockIdx.x;
  const int g0   = (b * NGRP) >> 8;
  const int NG   = (((b + 1) * NGRP) >> 8) - g0;   // 12 or 13
  const int row0 = g0 * 16;

  // ---- staging geometry: pair P = t + 512p -> 32B of one row ----
  const float* srcA[4];
  int ldsoff[4];
#pragma unroll
  for (int p = 0; p < 4; ++p) {
    int P  = t + 512 * p;
    int g  = P >> 7;
    int q  = P & 127;
    int r  = q >> 3;
    int kg = q & 7;
    srcA[p]   = A + (size_t)(row0 + g * 16 + r) * KDIM + kg * 8;
    ldsoff[p] = (g * 16 + r) * 64 + ((kg ^ (r & 7)) << 3);
  }
  const bool v3 = (t + 1536) < NG * 128;   // p=3 validity (p<3 always valid)

  const unsigned short* pb = Wb + (size_t)(16 * w + l15) * KDIM + kq * 8;
  const float hbv = hb[16 * w + l15];

  f32x4 acc[NGMAX];
#pragma unroll
  for (int g = 0; g < NGMAX; ++g) acc[g] = (f32x4){0.f, 0.f, 0.f, 0.f};

  f32x4 aR[4][2];
  s8v bA0, bA1, bB0, bB1;    // B-frag ring x2 (static regs, rule #20)

#define LOADA(CH) do {                                                        \
  const f32x4* q0 = reinterpret_cast<const f32x4*>(srcA[0] + (CH) * 64);      \
  aR[0][0] = q0[0]; aR[0][1] = q0[1];                                         \
  const f32x4* q1 = reinterpret_cast<const f32x4*>(srcA[1] + (CH) * 64);      \
  aR[1][0] = q1[0]; aR[1][1] = q1[1];                                         \
  const f32x4* q2 = reinterpret_cast<const f32x4*>(srcA[2] + (CH) * 64);      \
  aR[2][0] = q2[0]; aR[2][1] = q2[1];                                         \
  if (v3) {                                                                   \
    const f32x4* q3 = reinterpret_cast<const f32x4*>(srcA[3] + (CH) * 64);    \
    aR[3][0] = q3[0]; aR[3][1] = q3[1];                                       \
  }                                                                           \
} while (0)

#define CVTW1(P, BUFW) do {                                                   \
  s8v av;                                                                     \
  av[0] = f2bfs(aR[P][0][0]); av[1] = f2bfs(aR[P][0][1]);                     \
  av[2] = f2bfs(aR[P][0][2]); av[3] = f2bfs(aR[P][0][3]);                     \
  av[4] = f2bfs(aR[P][1][0]); av[5] = f2bfs(aR[P][1][1]);                     \
  av[6] = f2bfs(aR[P][1][2]); av[7] = f2bfs(aR[P][1][3]);                     \
  *reinterpret_cast<s8v*>(&(BUFW)[ldsoff[P]]) = av;                           \
} while (0)

#define CVTWRITE(BUFW) do {                                                   \
  CVTW1(0, BUFW); CVTW1(1, BUFW); CVTW1(2, BUFW);                             \
  if (v3) CVTW1(3, BUFW);                                                     \
} while (0)

#define LOADB(CH, B0, B1) do {                                                \
  B0 = *reinterpret_cast<const s8v*>(pb + (CH) * 64);                         \
  B1 = *reinterpret_cast<const s8v*>(pb + (CH) * 64 + 32);                    \
} while (0)

#define COMPUTE(BUFR, B0, B1) do {                                            \
  _Pragma("unroll")                                                           \
  for (int g = 0; g < NGMAX; ++g) {                                           \
    const s8v af = *reinterpret_cast<const s8v*>(                             \
        &(BUFR)[(g * 16 + l15) * 64 + ((kq ^ (l15 & 7)) << 3)]);              \
    acc[g] = __builtin_amdgcn_mfma_f32_16x16x32_bf16(af, B0, acc[g], 0, 0, 0);\
  }                                                                           \
  _Pragma("unroll")                                                           \
  for (int g = 0; g < NGMAX; ++g) {                                           \
    const s8v af = *reinterpret_cast<const s8v*>(                             \
        &(BUFR)[(g * 16 + l15) * 64 + (((4 + kq) ^ (l15 & 7)) << 3)]);        \
    acc[g] = __builtin_amdgcn_mfma_f32_16x16x32_bf16(af, B1, acc[g], 0, 0, 0);\
  }                                                                           \
} while (0)

#define BARRIER() do {                                                        \
  asm volatile("s_waitcnt lgkmcnt(0)" ::: "memory");                          \
  __builtin_amdgcn_s_barrier();                                               \
  __builtin_amdgcn_sched_barrier(0);                                          \
} while (0)

// One pipeline step for chunk S: barrier | compute S | cvt+write S+1 | issue S+2
#define STEP(S, BUFR, BUFW, B0, B1) do {                                      \
  BARRIER();                                                                  \
  COMPUTE(BUFR, B0, B1);                                                      \
  if ((S) + 1 < 64) CVTWRITE(BUFW);                                           \
  if ((S) + 2 < 64) { LOADA((S) + 2); LOADB((S) + 2, B0, B1); }               \
} while (0)

  // Prologue: A(0) -> LDS buf0; A(1) -> regs; B(0),B(1) -> reg sets
  LOADA(0);
  CVTWRITE(Abuf[0]);
  LOADA(1);
  LOADB(0, bA0, bA1);
  LOADB(1, bB0, bB1);

  for (int s2 = 0; s2 < 64; s2 += 2) {
    STEP(s2 + 0, Abuf[0], Abuf[1], bA0, bA1);
    STEP(s2 + 1, Abuf[1], Abuf[0], bB0, bB1);
  }

  // ---- epilogue: sign -> ballot -> u16 slices -> packed 128-bit rows ----
#pragma unroll
  for (int g = 0; g < NGMAX; ++g) {
#pragma unroll
    for (int r = 0; r < 4; ++r) {
      uint64_t mask = __ballot(acc[g][r] + hbv - 0.5f > 0.f);
      if (l15 == r)
        smb[g * 16 + (lane >> 4) * 4 + r][w] =
            (unsigned short)((mask >> (16 * (lane >> 4))) & 0xFFFFu);
    }
  }
  __syncthreads();
  const int rows = NG * 16;
  if (t < rows) {
    uint32_t w0 = (uint32_t)smb[t][0] | ((uint32_t)smb[t][1] << 16);
    uint32_t w1 = (uint32_t)smb[t][2] | ((uint32_t)smb[t][3] << 16);
    uint32_t w2 = (uint32_t)smb[t][4] | ((uint32_t)smb[t][5] << 16);
    uint32_t w3 = (uint32_t)smb[t][6] | ((uint32_t)smb[t][7] << 16);
    reinterpret_cast<u32x4*>(out_bits)[row0 + t] = (u32x4){w0, w1, w2, w3};
  }
}

// ---- Kernel hf: fp32 feature codes (tiny margins -> stay f32) ---------------
__global__ __launch_bounds__(64) void hf_kernel(
    const float* __restrict__ flat, const float* __restrict__ W,
    const float* __restrict__ hb, unsigned char* __restrict__ hf_bytes) {
  int bid = blockIdx.x;            // 8192 = 64 b * 128 n
  int n = bid & 127, b = bid >> 7;
  int lane = threadIdx.x;
  const f32x4* fa = reinterpret_cast<const f32x4*>(flat + (size_t)b * KDIM);
  const f32x4* wa = reinterpret_cast<const f32x4*>(W + (size_t)n * KDIM);
  float s = 0.f;
#pragma unroll 4
  for (int q = 0; q < 16; ++q) {
    f32x4 x = fa[lane + 64 * q], y = wa[lane + 64 * q];
    s += x[0] * y[0] + x[1] * y[1] + x[2] * y[2] + x[3] * y[3];
  }
  for (int o = 32; o; o >>= 1) s += __shfl_down(s, o, 64);
  if (lane == 0) hf_bytes[b * NH + n] = (s + hb[n] - 0.5f) > 0.f ? 1 : 0;
}

// ---- Kernel B: segmented argmin Hamming (ref tie-break) via atomicMin -------
__global__ __launch_bounds__(256) void argmin_part_kernel(
    const uint32_t* __restrict__ hm_bits, const unsigned char* __restrict__ hf_bytes,
    int M, unsigned int* __restrict__ keys) {
  __shared__ uint32_t red[256];
  const int b   = blockIdx.x & (BFEAT - 1);
  const int seg = blockIdx.x / BFEAT;
  const int span = (M + NSEG - 1) / NSEG;
  const int m0 = seg * span;
  int m1 = m0 + span; if (m1 > M) m1 = M;
  const int t = threadIdx.x;
  uint64_t hf0 = 0, hf1 = 0;
  const unsigned char* hfb = hf_bytes + b * NH;
  for (int c = 0; c < 64; ++c) {
    hf0 |= (uint64_t)(hfb[c] & 1u) << c;
    hf1 |= (uint64_t)(hfb[c + 64] & 1u) << c;
  }
  int hfsum = __popcll(hf0) + __popcll(hf1);
  uint32_t best = 0xFFFFFFFFu;
  for (int m = m0 + t; m < m1; m += 256) {
    u32x4 pv = reinterpret_cast<const u32x4*>(hm_bits)[m];
    uint64_t h0 = (uint64_t)pv[0] | ((uint64_t)pv[1] << 32);
    uint64_t h1 = (uint64_t)pv[2] | ((uint64_t)pv[3] << 32);
    int hmsum = __popcll(h0) + __popcll(h1);
    int dot   = __popcll(h0 & hf0) + __popcll(h1 & hf1);
    int hd    = hfsum + hmsum - 2 * dot;
    uint32_t key = ((uint32_t)hd << 16) | (uint32_t)m;   // M < 65536, HD <= 256
    best = best < key ? best : key;
  }
  red[t] = best;
  __syncthreads();
  for (int s = 128; s > 0; s >>= 1) {
    if (t < s) red[t] = red[t] < red[t + s] ? red[t] : red[t + s];
    __syncthreads();
  }
  if (t == 0) atomicMin(&keys[b], red[0]);   // device-scope, order-independent
}

// ---- Kernel C: gather nearest memory rows -----------------------------------
__global__ __launch_bounds__(256) void gather_kernel(
    const float* __restrict__ memory, const unsigned int* __restrict__ keys,
    float* __restrict__ out) {
  int b = blockIdx.x;
  int t = threadIdx.x;
  int m = (int)(keys[b] & 0xFFFFu);
  const f32x4* src = reinterpret_cast<const f32x4*>(memory + (size_t)m * KDIM);
  f32x4* dst = reinterpret_cast<f32x4*>(out + (size_t)b * KDIM);
#pragma unroll
  for (int c = 0; c < 4; ++c) dst[t + 256 * c] = src[t + 256 * c];
}

extern "C" void kernel_launch(void* const* d_in, const int* in_sizes, int n_in,
                              void* d_out, int out_size, void* d_ws, size_t ws_size,
                              hipStream_t stream) {
  const float* feature = (const float*)d_in[0];   // [64,64,8,8] == [64,4096]
  const float* memory  = (const float*)d_in[1];   // [50000,4096]
  const float* hash_W  = (const float*)d_in[2];   // [128,4096]
  const float* hash_b  = (const float*)d_in[3];   // [128]
  float* out = (float*)d_out;

  char* ws = (char*)d_ws;
  unsigned short* Wb       = (unsigned short*)ws;                       // 1,048,576 B
  uint32_t*       hm_bits  = (uint32_t*)(ws + 1048576);                 //   800,000 B
  unsigned char*  hf_bytes = (unsigned char*)(ws + 1048576 + 800000);   //     8,192 B
  unsigned int*   keys     = (unsigned int*)(ws + 1048576 + 800000 + 8192); //   256 B

  convert_w_kernel<<<(NH * KDIM / 4) / 256, 256, 0, stream>>>(hash_W, Wb, keys);
  hash_bits_kernel<<<NBLK, 512, 0, stream>>>(memory, Wb, hash_b, hm_bits);
  hf_kernel<<<BFEAT * NH, 64, 0, stream>>>(feature, hash_W, hash_b, hf_bytes);
  argmin_part_kernel<<<BFEAT * NSEG, 256, 0, stream>>>(hm_bits, hf_bytes, MMEM, keys);
  gather_kernel<<<BFEAT, 256, 0, stream>>>(memory, keys, out);
}